// Round 4
// baseline (250.776 us; speedup 1.0000x reference)
//
#include <hip/hip_runtime.h>

#define BATCH 512
#define SEQ   512
#define VOCAB 1000
#define EMB   100
#define UNITS 64

// ---------------------------------------------------------------------------
// Kernel 1: P[v][u] = sum_d emb[v][d] * Wxh[d][u] + b[u]   (VOCAB x UNITS)
// Hoists the entire input projection out of the time loop: xproj[b,t] depends
// only on the token id, and VOCAB=1000 << B*T=262144.
// ---------------------------------------------------------------------------
__global__ __launch_bounds__(64) void proj_kernel(
    const float* __restrict__ emb, const float* __restrict__ Wxh,
    const float* __restrict__ bias, float* __restrict__ P) {
  const int v = blockIdx.x;
  const int u = threadIdx.x;
  const float* e = emb + v * EMB;
  float acc = bias[u];
#pragma unroll 5
  for (int d = 0; d < EMB; ++d) acc += e[d] * Wxh[d * UNITS + u];
  P[v * UNITS + u] = acc;
}

// Broadcast lane `lane`'s value of x to all lanes (wave-uniform lane index
// -> v_readlane_b32 into an SGPR, consumed as scalar operand by v_fmac).
__device__ __forceinline__ float bcast(float x, int lane) {
  return __int_as_float(__builtin_amdgcn_readlane(__float_as_int(x), lane));
}

// ---------------------------------------------------------------------------
// Kernel 2: the sequential scan. One wave per batch row; lane j = unit j.
//   h[j] <- tanh(P[tok_t][j] + sum_i h[i]*Whh[i][j])
// Whh column j held in 64 VGPRs of lane j.
//
// amdgpu_waves_per_eu(1,1): r1-r3 showed VGPR_Count stuck at 44 — the GCN
// scheduler spills/sinks the 64 Whh loads into the time loop to chase
// occupancy (launch_bounds' min-waves arg only sets the LOWER bound of the
// waves-per-eu range, so the allocator still targets high occupancy).
// Pinning max waves/EU = 1 removes the incentive entirely; grid is only
// 512 waves (2/CU) so real occupancy is grid-limited either way.
// ---------------------------------------------------------------------------
__global__ __launch_bounds__(64)
__attribute__((amdgpu_waves_per_eu(1, 1)))
void scan_kernel(
    const int* __restrict__ tok, const float* __restrict__ P,
    const float* __restrict__ Whh, const float* __restrict__ Wout,
    const float* __restrict__ bout, float* __restrict__ out) {
  const int row  = blockIdx.x;
  const int lane = threadIdx.x;

  // Whh column for this lane: wh[i] = Whh[i][lane], pinned in VGPRs.
  float wh[UNITS];
#pragma unroll
  for (int i = 0; i < UNITS; ++i) {
    wh[i] = Whh[i * UNITS + lane];
    asm volatile("" : "+v"(wh[i]));  // opaque: forbid remat of the load
  }

  // All 512 tokens of this row, 64 per register (coalesced loads).
  int tokv[SEQ / 64];
  const int* trow = tok + row * SEQ;
#pragma unroll
  for (int c = 0; c < SEQ / 64; ++c) {
    tokv[c] = trow[c * 64 + lane];
    asm volatile("" : "+v"(tokv[c]));
  }

  float h = 0.f;

  // Prefetch P row for t=0.
  int tk0 = __builtin_amdgcn_readlane(tokv[0], 0);
  float a = P[tk0 * UNITS + lane];

#pragma unroll
  for (int c = 0; c < SEQ / 64; ++c) {
#pragma unroll 2
    for (int tt = 0; tt < 64; ++tt) {
      float a_cur = a;
      // Prefetch next timestep's P row (tt=63 issues a redundant in-chunk
      // load; the real cross-chunk prefetch happens after the loop).
      int ntt = (tt + 1) & 63;
      int tkn = __builtin_amdgcn_readlane(tokv[c], ntt);
      a = P[tkn * UNITS + lane];

      // s_j = a_cur + sum_i h[i] * Whh[i][j], 8 accumulators: dependent
      // fmac chain is 8 deep (~32 cyc), well under the per-step issue
      // stream.
      float s0 = a_cur, s1 = 0.f, s2 = 0.f, s3 = 0.f;
      float s4 = 0.f, s5 = 0.f, s6 = 0.f, s7 = 0.f;
#pragma unroll
      for (int i = 0; i < UNITS; i += 8) {
        s0 += bcast(h, i + 0) * wh[i + 0];
        s1 += bcast(h, i + 1) * wh[i + 1];
        s2 += bcast(h, i + 2) * wh[i + 2];
        s3 += bcast(h, i + 3) * wh[i + 3];
        s4 += bcast(h, i + 4) * wh[i + 4];
        s5 += bcast(h, i + 5) * wh[i + 5];
        s6 += bcast(h, i + 6) * wh[i + 6];
        s7 += bcast(h, i + 7) * wh[i + 7];
      }
      float s = ((s0 + s1) + (s2 + s3)) + ((s4 + s5) + (s6 + s7));

      // tanh(s) = 1 - 2/(exp(2s)+1)  (safe at both extremes)
      float e = __expf(2.f * s);
      h = 1.f - 2.f / (e + 1.f);
    }
    if (c + 1 < SEQ / 64) {
      int tkb = __builtin_amdgcn_readlane(tokv[c + 1], 0);
      a = P[tkb * UNITS + lane];
    }
  }

  // out[row] = sigmoid(sum_j h[j]*Wout[j] + bout)
  float p = h * Wout[lane];
#pragma unroll
  for (int off = 32; off > 0; off >>= 1) p += __shfl_xor(p, off);
  if (lane == 0) out[row] = 1.f / (1.f + __expf(-(p + bout[0])));
}

extern "C" void kernel_launch(void* const* d_in, const int* in_sizes, int n_in,
                              void* d_out, int out_size, void* d_ws, size_t ws_size,
                              hipStream_t stream) {
  const int*   tok  = (const int*)  d_in[0];  // [BATCH, SEQ] int32
  const float* emb  = (const float*)d_in[1];  // [VOCAB, EMB]
  const float* Wxh  = (const float*)d_in[2];  // [EMB, UNITS]
  const float* Whh  = (const float*)d_in[3];  // [UNITS, UNITS]
  const float* bias = (const float*)d_in[4];  // [UNITS]
  const float* Wout = (const float*)d_in[5];  // [UNITS, 1]
  const float* bout = (const float*)d_in[6];  // [1]
  float* out = (float*)d_out;                 // [BATCH, 1] fp32

  float* P = (float*)d_ws;                    // VOCAB*UNITS fp32 = 256 KB

  proj_kernel<<<VOCAB, 64, 0, stream>>>(emb, Wxh, bias, P);
  scan_kernel<<<BATCH, 64, 0, stream>>>(tok, P, Whh, Wout, bout, out);
}

// Round 5
// 184.818 us; speedup vs baseline: 1.3569x; 1.3569x over previous
//
#include <hip/hip_runtime.h>

#define BATCH 512
#define SEQ   512
#define VOCAB 1000
#define EMB   100
#define UNITS 64

typedef float v2f __attribute__((ext_vector_type(2)));
typedef float v4f __attribute__((ext_vector_type(4)));

// ---------------------------------------------------------------------------
// Kernel 1: P[v][u] = sum_d emb[v][d] * Wxh[d][u] + b[u]   (VOCAB x UNITS)
// ---------------------------------------------------------------------------
__global__ __launch_bounds__(64) void proj_kernel(
    const float* __restrict__ emb, const float* __restrict__ Wxh,
    const float* __restrict__ bias, float* __restrict__ P) {
  const int v = blockIdx.x;
  const int u = threadIdx.x;
  const float* e = emb + v * EMB;
  float acc = bias[u];
#pragma unroll 5
  for (int d = 0; d < EMB; ++d) acc += e[d] * Wxh[d * UNITS + u];
  P[v * UNITS + u] = acc;
}

// ---------------------------------------------------------------------------
// Kernel 2: sequential scan, one wave per batch row, lane j = unit j.
//   h[j] <- tanh(P[tok_t][j] + sum_i h[i]*Whh[i][j])
//
// r4 post-mortem: with wh[] register-resident (VGPR 132) timing was UNCHANGED
// -> the bottleneck is the 64 v_readlane->v_fmac dependent pairs per step
// (~9 cyc each: SGPR-write->VALU-read hazards + tight pairing). This version
// broadcasts h through LDS instead: 1 ds_write_b32 + 16 broadcast
// ds_read_b128 per step (DS pipe, parallel to VALU, zero bank conflicts),
// and the dot becomes 32 v_pk_fma_f32 on pure VGPR operands.
// Latency-bound regime: wall = 512 steps x per-step critical path; target
// ~300 cyc/step vs r4's 871.
// ---------------------------------------------------------------------------
__global__ __launch_bounds__(64)
__attribute__((amdgpu_waves_per_eu(1, 1)))
void scan_kernel(
    const int* __restrict__ tok, const float* __restrict__ P,
    const float* __restrict__ Whh, const float* __restrict__ Wout,
    const float* __restrict__ bout, float* __restrict__ out) {
  const int row  = blockIdx.x;
  const int lane = threadIdx.x;

  __shared__ __align__(16) v4f hs4[UNITS / 4];  // 64 floats, broadcast buffer
  float* hsf = (float*)hs4;

  // Whh columns for this lane, as 32 packed pairs: wh2[k] = {Whh[2k][lane],
  // Whh[2k+1][lane]} — pinned so the allocator can't sink the loads.
  v2f wh2[UNITS / 2];
#pragma unroll
  for (int k = 0; k < UNITS / 2; ++k) {
    float wx = Whh[(2 * k + 0) * UNITS + lane];
    float wy = Whh[(2 * k + 1) * UNITS + lane];
    asm volatile("" : "+v"(wx), "+v"(wy));
    wh2[k].x = wx;
    wh2[k].y = wy;
  }

  // All 512 tokens of this row, 64 per register (coalesced loads).
  int tokv[SEQ / 64];
  const int* trow = tok + row * SEQ;
#pragma unroll
  for (int c = 0; c < SEQ / 64; ++c) {
    tokv[c] = trow[c * 64 + lane];
    asm volatile("" : "+v"(tokv[c]));
  }

  // h_0 = 0 in the broadcast buffer (single wave: LDS ops are in-order,
  // no barrier needed anywhere in this kernel).
  hsf[lane] = 0.f;

  // Prefetch P row for t=0.
  int tk0 = __builtin_amdgcn_readlane(tokv[0], 0);
  float a = P[(long)tk0 * UNITS + lane];

#pragma unroll
  for (int c = 0; c < SEQ / 64; ++c) {
#pragma unroll 2
    for (int tt = 0; tt < 64; ++tt) {
      float a_cur = a;
      // Prefetch next timestep's P row; consumed only at the END of the
      // next step's reduce, so it has ~1.5 steps to land.
      int ntt = (tt + 1) & 63;
      int tkn = __builtin_amdgcn_readlane(tokv[c], ntt);
      a = P[(long)tkn * UNITS + lane];

      // Broadcast-read h (16x ds_read_b128, all lanes same address) and
      // accumulate with packed fp32 FMAs. 4 v2f accumulators -> dependent
      // chains of 8 pk_fma (~32 cyc), hidden under the DS stream.
      v2f acc0 = {0.f, 0.f}, acc1 = {0.f, 0.f};
      v2f acc2 = {0.f, 0.f}, acc3 = {0.f, 0.f};
#pragma unroll
      for (int q = 0; q < UNITS / 4; ++q) {
        v4f hq = hs4[q];
        v2f lo; lo.x = hq.x; lo.y = hq.y;
        v2f hi; hi.x = hq.z; hi.y = hq.w;
        if (q & 1) {
          acc2 += lo * wh2[2 * q + 0];
          acc3 += hi * wh2[2 * q + 1];
        } else {
          acc0 += lo * wh2[2 * q + 0];
          acc1 += hi * wh2[2 * q + 1];
        }
      }
      v2f r = (acc0 + acc1) + (acc2 + acc3);
      float s = (r.x + r.y) + a_cur;

      // tanh(s) = 1 - 2/(exp(2s)+1)  (safe at both extremes)
      float e = __expf(2.f * s);
      float h = 1.f - 2.f / (e + 1.f);

      // Publish h for the next step (same-wave LDS is in-order; the next
      // iteration's ds_reads will see this write).
      hsf[lane] = h;
    }
    if (c + 1 < SEQ / 64) {
      int tkb = __builtin_amdgcn_readlane(tokv[c + 1], 0);
      a = P[(long)tkb * UNITS + lane];
    }
  }

  // out[row] = sigmoid(sum_j h[j]*Wout[j] + bout)
  float p = hsf[lane] * Wout[lane];
#pragma unroll
  for (int off = 32; off > 0; off >>= 1) p += __shfl_xor(p, off);
  if (lane == 0) out[row] = 1.f / (1.f + __expf(-(p + bout[0])));
}

extern "C" void kernel_launch(void* const* d_in, const int* in_sizes, int n_in,
                              void* d_out, int out_size, void* d_ws, size_t ws_size,
                              hipStream_t stream) {
  const int*   tok  = (const int*)  d_in[0];  // [BATCH, SEQ] int32
  const float* emb  = (const float*)d_in[1];  // [VOCAB, EMB]
  const float* Wxh  = (const float*)d_in[2];  // [EMB, UNITS]
  const float* Whh  = (const float*)d_in[3];  // [UNITS, UNITS]
  const float* bias = (const float*)d_in[4];  // [UNITS]
  const float* Wout = (const float*)d_in[5];  // [UNITS, 1]
  const float* bout = (const float*)d_in[6];  // [1]
  float* out = (float*)d_out;                 // [BATCH, 1] fp32

  float* P = (float*)d_ws;                    // VOCAB*UNITS fp32 = 256 KB

  proj_kernel<<<VOCAB, 64, 0, stream>>>(emb, Wxh, bias, P);
  scan_kernel<<<BATCH, 64, 0, stream>>>(tok, P, Whh, Wout, bout, out);
}